// Round 12
// baseline (93.164 us; speedup 1.0000x reference)
//
#include <hip/hip_runtime.h>
#include <hip/hip_fp16.h>
#include <math.h>
#include <string.h>

#define WSZ 11
#define TX 64
#define TY 48
#define IN_H 58            // TY + 10
#define SIP 66             // si row stride in uint (half2) units
#define NTHREADS 256
#define TILES_Y 11         // ceil(512/48); last row covers y 480..511 (partial)

struct GWH { unsigned g2[WSZ]; };   // half2-packed taps

__device__ __forceinline__ unsigned h2u(__half2 h) {
  return __builtin_bit_cast(unsigned, h);
}
__device__ __forceinline__ __half2 u2h(unsigned u) {
  return __builtin_bit_cast(__half2, u);
}

// m1 = mu1, m2 = mu2, mss = E[a^2+b^2], m12 = E[ab]
__device__ __forceinline__ float ssim_px(float m1, float m2, float mss, float m12) {
  const float C1 = 0.0001f, C2 = 0.0009f;
  const float mu1s = m1 * m1, mu2s = m2 * m2, mu12 = m1 * m2;
  const float num = (2.f * mu12 + C1) * (2.f * (m12 - mu12) + C2);
  const float den = (mu1s + mu2s + C1) * (mss - mu1s - mu2s + C2);
  return num * __builtin_amdgcn_rcpf(den);
}

// 18-float window (8 output px), edge-clamped + masked variant.
__device__ __forceinline__ void loadwin18_edge(const float* __restrict__ rp,
                                               int oS0, int oQ1, int oQ2, int oQ3,
                                               int oQ4, int oS1,
                                               float mS0, float mQ1, float mQ4,
                                               float mS1, float v[18]) {
  const float s0 = rp[oS0];
  const float4 q1 = *(const float4*)(rp + oQ1);
  const float4 q2 = *(const float4*)(rp + oQ2);
  const float4 q3 = *(const float4*)(rp + oQ3);
  const float4 q4 = *(const float4*)(rp + oQ4);
  const float s1 = rp[oS1];
  v[0] = s0 * mS0;
  v[1] = q1.x * mQ1;  v[2] = q1.y * mQ1;  v[3] = q1.z * mQ1;  v[4] = q1.w * mQ1;
  v[5] = q2.x;  v[6] = q2.y;  v[7] = q2.z;  v[8] = q2.w;
  v[9] = q3.x;  v[10] = q3.y; v[11] = q3.z; v[12] = q3.w;
  v[13] = q4.x * mQ4; v[14] = q4.y * mQ4; v[15] = q4.z * mQ4; v[16] = q4.w * mQ4;
  v[17] = s1 * mS1;
}

// interior variant: no clamps, no masks
__device__ __forceinline__ void loadwin18_fast(const float* __restrict__ rp,
                                               int x0, float v[18]) {
  const float s0 = rp[x0 - 5];
  const float4 q1 = *(const float4*)(rp + x0 - 4);
  const float4 q2 = *(const float4*)(rp + x0);
  const float4 q3 = *(const float4*)(rp + x0 + 4);
  const float4 q4 = *(const float4*)(rp + x0 + 8);
  const float s1 = rp[x0 + 12];
  v[0] = s0;
  v[1] = q1.x;  v[2] = q1.y;  v[3] = q1.z;  v[4] = q1.w;
  v[5] = q2.x;  v[6] = q2.y;  v[7] = q2.z;  v[8] = q2.w;
  v[9] = q3.x;  v[10] = q3.y; v[11] = q3.z; v[12] = q3.w;
  v[13] = q4.x; v[14] = q4.y; v[15] = q4.z; v[16] = q4.w;
  v[17] = s1;
}

__global__ __launch_bounds__(NTHREADS) void ssim_main_kernel(
    const float* __restrict__ img1, const float* __restrict__ img2,
    float* __restrict__ partials, GWH wh)
{
  // streams: si0 = (a,b), si1 = (a^2+b^2, a*b), half2 per px
  __shared__ __align__(16) unsigned si0[IN_H][SIP];  // 15,312 B
  __shared__ __align__(16) unsigned si1[IN_H][SIP];  // 15,312 B
  __shared__ float sred[NTHREADS / 64];

  const int tid = threadIdx.x;

  // tile decode: one tile per block (tx fastest, then ty, then plane)
  int b = blockIdx.x;
  const int tx = b & 7;        b >>= 3;
  const int ty = b % TILES_Y;  b /= TILES_Y;
  const float* __restrict__ p1 = img1 + (size_t)b * 262144;
  const float* __restrict__ p2 = img2 + (size_t)b * 262144;
  const int gy0 = ty * TY - 5;
  const bool edgeX = (tx == 0) | (tx == 7);

  // packed taps in VGPRs
  __half2 gh[WSZ];
#pragma unroll
  for (int k = 0; k < WSZ; k++) gh[k] = u2h(wh.g2[k]);

  // ---- per-thread h-geometry (jj fixed: items stride 256, 256%8==0) ----
  const int jj = tid & 7;
  const int x0 = tx * TX + 8 * jj;
  const int iS0 = x0 - 5;
  const int oS0 = iS0 < 0 ? 0 : iS0;
  const float mS0 = iS0 < 0 ? 0.f : 1.f;
  const int iQ1 = x0 - 4;
  const int oQ1 = iQ1 < 0 ? 0 : iQ1;
  const float mQ1 = iQ1 < 0 ? 0.f : 1.f;
  const int oQ2 = x0;
  const int oQ3 = x0 + 4;
  const int iQ4 = x0 + 8;
  const int oQ4 = iQ4 > 508 ? 508 : iQ4;
  const float mQ4 = iQ4 > 508 ? 0.f : 1.f;
  const int iS1 = x0 + 12;
  const int oS1 = iS1 > 511 ? 511 : iS1;
  const float mS1 = iS1 > 511 ? 0.f : 1.f;

  // ---- horizontal pass: 8 px per item, 464 items ----
  for (int it = tid; it < IN_H * 8; it += NTHREADS) {
    const int r = it >> 3;
    const int gy = gy0 + r;
    unsigned* w0 = &si0[r][8 * jj];
    unsigned* w1 = &si1[r][8 * jj];
    if ((unsigned)gy < 512u) {
      const float* rp1 = p1 + ((size_t)gy << 9);
      const float* rp2 = p2 + ((size_t)gy << 9);
      float a[18], bb[18];
      if (edgeX) {
        loadwin18_edge(rp1, oS0, oQ1, oQ2, oQ3, oQ4, oS1, mS0, mQ1, mQ4, mS1, a);
        loadwin18_edge(rp2, oS0, oQ1, oQ2, oQ3, oQ4, oS1, mS0, mQ1, mQ4, mS1, bb);
      } else {
        loadwin18_fast(rp1, x0, a);
        loadwin18_fast(rp2, x0, bb);
      }
      __half2 vab[18], vsb[18];
#pragma unroll
      for (int q = 0; q < 18; q++) {
        vab[q] = __floats2half2_rn(a[q], bb[q]);
        vsb[q] = __floats2half2_rn(fmaf(a[q], a[q], bb[q] * bb[q]), a[q] * bb[q]);
      }
      __half2 hA[8], hS[8];
#pragma unroll
      for (int x = 0; x < 8; x++) {
        hA[x] = __hmul2(gh[0], vab[x]);
        hS[x] = __hmul2(gh[0], vsb[x]);
      }
#pragma unroll
      for (int k = 1; k < WSZ; k++) {
#pragma unroll
        for (int x = 0; x < 8; x++) {
          hA[x] = __hfma2(gh[k], vab[x + k], hA[x]);
          hS[x] = __hfma2(gh[k], vsb[x + k], hS[x]);
        }
      }
      *(uint4*)&w0[0] = make_uint4(h2u(hA[0]), h2u(hA[1]), h2u(hA[2]), h2u(hA[3]));
      *(uint4*)&w0[4] = make_uint4(h2u(hA[4]), h2u(hA[5]), h2u(hA[6]), h2u(hA[7]));
      *(uint4*)&w1[0] = make_uint4(h2u(hS[0]), h2u(hS[1]), h2u(hS[2]), h2u(hS[3]));
      *(uint4*)&w1[4] = make_uint4(h2u(hS[4]), h2u(hS[5]), h2u(hS[6]), h2u(hS[7]));
    } else {
      const uint4 z = make_uint4(0u, 0u, 0u, 0u);
      *(uint4*)&w0[0] = z; *(uint4*)&w0[4] = z;
      *(uint4*)&w1[0] = z; *(uint4*)&w1[4] = z;
    }
  }
  __syncthreads();

  // ---- vertical pass + SSIM: 4x x 3y per thread (256 items) ----
  float accSum = 0.f;
  {
    const int j = tid & 15, yi = tid >> 4;
    const int y0 = 3 * yi;               // 0..45
    const int oyBase = ty * TY + y0;     // output row of o=0
    __half2 accA[3][4], accS[3][4];      // [y-output][px]
#pragma unroll
    for (int o = 0; o < 3; o++)
#pragma unroll
      for (int p = 0; p < 4; p++) { accA[o][p] = u2h(0u); accS[o][p] = u2h(0u); }
#pragma unroll
    for (int k = 0; k < WSZ + 2; k++) {
      const int rr = y0 + k;
      const uint4 ua = *(const uint4*)&si0[rr][4 * j];
      const uint4 us = *(const uint4*)&si1[rr][4 * j];
      const __half2 va[4] = {u2h(ua.x), u2h(ua.y), u2h(ua.z), u2h(ua.w)};
      const __half2 vs[4] = {u2h(us.x), u2h(us.y), u2h(us.z), u2h(us.w)};
#pragma unroll
      for (int o = 0; o < 3; o++) {
        if (k >= o && k - o < WSZ) {
          const __half2 g2 = gh[k - o];
#pragma unroll
          for (int p = 0; p < 4; p++) {
            accA[o][p] = __hfma2(g2, va[p], accA[o][p]);
            accS[o][p] = __hfma2(g2, vs[p], accS[o][p]);
          }
        }
      }
    }
#pragma unroll
    for (int o = 0; o < 3; o++) {
      if (oyBase + o < 512) {            // partial last tile row
#pragma unroll
        for (int p = 0; p < 4; p++) {
          const float2 mab = __half22float2(accA[o][p]);
          const float2 msb = __half22float2(accS[o][p]);
          accSum += ssim_px(mab.x, mab.y, msb.x, msb.y);
        }
      }
    }
  }

  // ---- block reduction ----
  for (int off = 32; off > 0; off >>= 1)
    accSum += __shfl_down(accSum, off, 64);
  if ((tid & 63) == 0) sred[tid >> 6] = accSum;
  __syncthreads();
  if (tid == 0) {
    float s = 0.f;
#pragma unroll
    for (int i = 0; i < NTHREADS / 64; i++) s += sred[i];
    partials[blockIdx.x] = s;
  }
}

__global__ __launch_bounds__(256) void ssim_final_kernel(
    const float* __restrict__ partials, float* __restrict__ out,
    int n, double invN)
{
  __shared__ double sred[4];
  const int tid = threadIdx.x;
  double s = 0.0;
  for (int i = tid; i < n; i += 256) s += (double)partials[i];
  for (int off = 32; off > 0; off >>= 1)
    s += __shfl_down(s, off, 64);
  if ((tid & 63) == 0) sred[tid >> 6] = s;
  __syncthreads();
  if (tid == 0) {
    double tot = 0.0;
#pragma unroll
    for (int i = 0; i < 4; i++) tot += sred[i];
    out[0] = (float)(1.0 - tot * invN);
  }
}

extern "C" void kernel_launch(void* const* d_in, const int* in_sizes, int n_in,
                              void* d_out, int out_size, void* d_ws, size_t ws_size,
                              hipStream_t stream) {
  const float* img1 = (const float*)d_in[0];
  const float* img2 = (const float*)d_in[1];
  float* out = (float*)d_out;
  float* partials = (float*)d_ws;

  const int planes = in_sizes[0] / (512 * 512);   // 96
  const int nBlocks = planes * 8 * TILES_Y;       // 8448, one tile each

  GWH wh;
  {
    double g[WSZ], sum = 0.0;
    for (int i = 0; i < WSZ; i++) {
      const double x = (double)(i - WSZ / 2);
      g[i] = exp(-(x * x) / (2.0 * 1.5 * 1.5));
      sum += g[i];
    }
    for (int i = 0; i < WSZ; i++) {
      const _Float16 hf = (_Float16)(float)(g[i] / sum);
      unsigned short hb;
      memcpy(&hb, &hf, 2);
      wh.g2[i] = (unsigned)hb | ((unsigned)hb << 16);
    }
  }

  const double invN = 1.0 / (double)in_sizes[0];

  ssim_main_kernel<<<nBlocks, NTHREADS, 0, stream>>>(img1, img2, partials, wh);
  ssim_final_kernel<<<1, 256, 0, stream>>>(partials, out, nBlocks, invN);
}

// Round 13
// 85.726 us; speedup vs baseline: 1.0868x; 1.0868x over previous
//
#include <hip/hip_runtime.h>
#include <hip/hip_fp16.h>
#include <math.h>
#include <string.h>

#define WSZ 11
#define TX 64
#define TY 64
#define RING 42            // LDS ring rows (= 32 + 10)
#define SIP 66             // si row stride in uint (half2) units
#define NTHREADS 256

struct GWH { unsigned g2[WSZ]; };   // half2-packed taps

__device__ __forceinline__ unsigned h2u(__half2 h) {
  return __builtin_bit_cast(unsigned, h);
}
__device__ __forceinline__ __half2 u2h(unsigned u) {
  return __builtin_bit_cast(__half2, u);
}

// m1 = mu1, m2 = mu2, mss = E[a^2+b^2], m12 = E[ab]
__device__ __forceinline__ float ssim_px(float m1, float m2, float mss, float m12) {
  const float C1 = 0.0001f, C2 = 0.0009f;
  const float mu1s = m1 * m1, mu2s = m2 * m2, mu12 = m1 * m2;
  const float num = (2.f * mu12 + C1) * (2.f * (m12 - mu12) + C2);
  const float den = (mu1s + mu2s + C1) * (mss - mu1s - mu2s + C2);
  return num * __builtin_amdgcn_rcpf(den);
}

// 18-float window (8 output px), edge-clamped + masked variant.
__device__ __forceinline__ void loadwin18_edge(const float* __restrict__ rp,
                                               int oS0, int oQ1, int oQ2, int oQ3,
                                               int oQ4, int oS1,
                                               float mS0, float mQ1, float mQ4,
                                               float mS1, float v[18]) {
  const float s0 = rp[oS0];
  const float4 q1 = *(const float4*)(rp + oQ1);
  const float4 q2 = *(const float4*)(rp + oQ2);
  const float4 q3 = *(const float4*)(rp + oQ3);
  const float4 q4 = *(const float4*)(rp + oQ4);
  const float s1 = rp[oS1];
  v[0] = s0 * mS0;
  v[1] = q1.x * mQ1;  v[2] = q1.y * mQ1;  v[3] = q1.z * mQ1;  v[4] = q1.w * mQ1;
  v[5] = q2.x;  v[6] = q2.y;  v[7] = q2.z;  v[8] = q2.w;
  v[9] = q3.x;  v[10] = q3.y; v[11] = q3.z; v[12] = q3.w;
  v[13] = q4.x * mQ4; v[14] = q4.y * mQ4; v[15] = q4.z * mQ4; v[16] = q4.w * mQ4;
  v[17] = s1 * mS1;
}

// interior variant: no clamps, no masks
__device__ __forceinline__ void loadwin18_fast(const float* __restrict__ rp,
                                               int x0, float v[18]) {
  const float s0 = rp[x0 - 5];
  const float4 q1 = *(const float4*)(rp + x0 - 4);
  const float4 q2 = *(const float4*)(rp + x0);
  const float4 q3 = *(const float4*)(rp + x0 + 4);
  const float4 q4 = *(const float4*)(rp + x0 + 8);
  const float s1 = rp[x0 + 12];
  v[0] = s0;
  v[1] = q1.x;  v[2] = q1.y;  v[3] = q1.z;  v[4] = q1.w;
  v[5] = q2.x;  v[6] = q2.y;  v[7] = q2.z;  v[8] = q2.w;
  v[9] = q3.x;  v[10] = q3.y; v[11] = q3.z; v[12] = q3.w;
  v[13] = q4.x; v[14] = q4.y; v[15] = q4.z; v[16] = q4.w;
  v[17] = s1;
}

// One h item: image row gy0+R_, ring slot SLOT_, columns x0..x0+7.
#define H_BODY(R_, SLOT_)                                                      \
  {                                                                            \
    const int gy = gy0 + (R_);                                                 \
    unsigned* w0 = &si0[(SLOT_)][8 * jj];                                      \
    unsigned* w1 = &si1[(SLOT_)][8 * jj];                                      \
    if ((unsigned)gy < 512u) {                                                 \
      const float* rp1 = p1 + ((size_t)gy << 9);                               \
      const float* rp2 = p2 + ((size_t)gy << 9);                               \
      float a[18], bb[18];                                                     \
      if (edgeX) {                                                             \
        loadwin18_edge(rp1, oS0, oQ1, oQ2, oQ3, oQ4, oS1, mS0, mQ1, mQ4, mS1, a); \
        loadwin18_edge(rp2, oS0, oQ1, oQ2, oQ3, oQ4, oS1, mS0, mQ1, mQ4, mS1, bb); \
      } else {                                                                 \
        loadwin18_fast(rp1, x0, a);                                            \
        loadwin18_fast(rp2, x0, bb);                                           \
      }                                                                        \
      __half2 vab[18], vsb[18];                                                \
      _Pragma("unroll")                                                        \
      for (int q = 0; q < 18; q++) {                                           \
        vab[q] = __floats2half2_rn(a[q], bb[q]);                               \
        vsb[q] = __floats2half2_rn(fmaf(a[q], a[q], bb[q] * bb[q]),            \
                                   a[q] * bb[q]);                              \
      }                                                                        \
      __half2 hA[8], hS[8];                                                    \
      _Pragma("unroll")                                                        \
      for (int x = 0; x < 8; x++) {                                            \
        hA[x] = __hmul2(gh[0], vab[x]);                                        \
        hS[x] = __hmul2(gh[0], vsb[x]);                                        \
      }                                                                        \
      _Pragma("unroll")                                                        \
      for (int k = 1; k < WSZ; k++) {                                          \
        _Pragma("unroll")                                                      \
        for (int x = 0; x < 8; x++) {                                          \
          hA[x] = __hfma2(gh[k], vab[x + k], hA[x]);                           \
          hS[x] = __hfma2(gh[k], vsb[x + k], hS[x]);                           \
        }                                                                      \
      }                                                                        \
      *(uint4*)&w0[0] = make_uint4(h2u(hA[0]), h2u(hA[1]), h2u(hA[2]), h2u(hA[3])); \
      *(uint4*)&w0[4] = make_uint4(h2u(hA[4]), h2u(hA[5]), h2u(hA[6]), h2u(hA[7])); \
      *(uint4*)&w1[0] = make_uint4(h2u(hS[0]), h2u(hS[1]), h2u(hS[2]), h2u(hS[3])); \
      *(uint4*)&w1[4] = make_uint4(h2u(hS[4]), h2u(hS[5]), h2u(hS[6]), h2u(hS[7])); \
    } else {                                                                   \
      const uint4 z = make_uint4(0u, 0u, 0u, 0u);                              \
      *(uint4*)&w0[0] = z; *(uint4*)&w0[4] = z;                                \
      *(uint4*)&w1[0] = z; *(uint4*)&w1[4] = z;                                \
    }                                                                          \
  }

// One v phase: 32 output rows (local BASE_..BASE_+31), 2y x 4px per thread.
// WRAP_: ring-wrap row index (phase B).
#define V_PHASE(BASE_, WRAP_)                                                  \
  {                                                                            \
    const int y0 = 2 * yi;                                                     \
    __half2 accA[2][4], accS[2][4];                                            \
    _Pragma("unroll")                                                          \
    for (int o = 0; o < 2; o++)                                                \
      _Pragma("unroll")                                                        \
      for (int p = 0; p < 4; p++) { accA[o][p] = u2h(0u); accS[o][p] = u2h(0u); } \
    _Pragma("unroll")                                                          \
    for (int k = 0; k < WSZ + 1; k++) {                                        \
      int rr = (BASE_) + y0 + k;                                               \
      if (WRAP_) rr = rr >= RING ? rr - RING : rr;                             \
      const uint4 ua = *(const uint4*)&si0[rr][4 * j];                         \
      const uint4 us = *(const uint4*)&si1[rr][4 * j];                         \
      const __half2 va[4] = {u2h(ua.x), u2h(ua.y), u2h(ua.z), u2h(ua.w)};      \
      const __half2 vs[4] = {u2h(us.x), u2h(us.y), u2h(us.z), u2h(us.w)};      \
      _Pragma("unroll")                                                        \
      for (int o = 0; o < 2; o++) {                                            \
        if (k >= o && k - o < WSZ) {                                           \
          const __half2 g2 = gh[k - o];                                        \
          _Pragma("unroll")                                                    \
          for (int p = 0; p < 4; p++) {                                        \
            accA[o][p] = __hfma2(g2, va[p], accA[o][p]);                       \
            accS[o][p] = __hfma2(g2, vs[p], accS[o][p]);                       \
          }                                                                    \
        }                                                                      \
      }                                                                        \
    }                                                                          \
    _Pragma("unroll")                                                          \
    for (int o = 0; o < 2; o++)                                                \
      _Pragma("unroll")                                                        \
      for (int p = 0; p < 4; p++) {                                            \
        const float2 mab = __half22float2(accA[o][p]);                         \
        const float2 msb = __half22float2(accS[o][p]);                         \
        accSum += ssim_px(mab.x, mab.y, msb.x, msb.y);                         \
      }                                                                        \
  }

__global__ __launch_bounds__(NTHREADS) void ssim_main_kernel(
    const float* __restrict__ img1, const float* __restrict__ img2,
    float* __restrict__ partials, GWH wh)
{
  // ring: 42 rows x 64 px x (2 streams x half2) = 22.2 KB -> 7 blocks/CU
  __shared__ __align__(16) unsigned si0[RING][SIP];
  __shared__ __align__(16) unsigned si1[RING][SIP];
  __shared__ float sred[NTHREADS / 64];

  const int tid = threadIdx.x;

  // tile decode: one 64x64 tile per block
  int b = blockIdx.x;
  const int tx = b & 7;  b >>= 3;
  const int ty = b & 7;  b >>= 3;
  const float* __restrict__ p1 = img1 + (size_t)b * 262144;
  const float* __restrict__ p2 = img2 + (size_t)b * 262144;
  const int gy0 = ty * TY - 5;
  const bool edgeX = (tx == 0) | (tx == 7);

  // packed taps in VGPRs
  __half2 gh[WSZ];
#pragma unroll
  for (int k = 0; k < WSZ; k++) gh[k] = u2h(wh.g2[k]);

  // ---- per-thread h-geometry (jj fixed: item stride 256 == 0 mod 8) ----
  const int jj = tid & 7;
  const int x0 = tx * TX + 8 * jj;
  const int iS0 = x0 - 5;
  const int oS0 = iS0 < 0 ? 0 : iS0;
  const float mS0 = iS0 < 0 ? 0.f : 1.f;
  const int iQ1 = x0 - 4;
  const int oQ1 = iQ1 < 0 ? 0 : iQ1;
  const float mQ1 = iQ1 < 0 ? 0.f : 1.f;
  const int oQ2 = x0;
  const int oQ3 = x0 + 4;
  const int iQ4 = x0 + 8;
  const int oQ4 = iQ4 > 508 ? 508 : iQ4;
  const float mQ4 = iQ4 > 508 ? 0.f : 1.f;
  const int iS1 = x0 + 12;
  const int oS1 = iS1 > 511 ? 511 : iS1;
  const float mS1 = iS1 > 511 ? 0.f : 1.f;

  // v-pass thread geometry
  const int j = tid & 15, yi = tid >> 4;

  float accSum = 0.f;

  // ---- phase A: h rows 0..41 -> slots 0..41 (336 items) ----
  for (int it = tid; it < RING * 8; it += NTHREADS) {
    const int r = it >> 3;
    H_BODY(r, r)
  }
  __syncthreads();

  // ---- phase A: v out rows 0..31 (reads slots 0..41) ----
  V_PHASE(0, false)
  __syncthreads();

  // ---- phase B: h rows 42..73 -> slots 0..31 (256 items, 1/thread) ----
  {
    const int r = RING + (tid >> 3);
    H_BODY(r, r - RING)
  }
  __syncthreads();

  // ---- phase B: v out rows 32..63 (reads slots wrapped) ----
  V_PHASE(32, true)

  // ---- block reduction ----
  for (int off = 32; off > 0; off >>= 1)
    accSum += __shfl_down(accSum, off, 64);
  if ((tid & 63) == 0) sred[tid >> 6] = accSum;
  __syncthreads();
  if (tid == 0) {
    float s = 0.f;
#pragma unroll
    for (int i = 0; i < NTHREADS / 64; i++) s += sred[i];
    partials[blockIdx.x] = s;
  }
}

__global__ __launch_bounds__(256) void ssim_final_kernel(
    const float* __restrict__ partials, float* __restrict__ out,
    int n, double invN)
{
  __shared__ double sred[4];
  const int tid = threadIdx.x;
  double s = 0.0;
  for (int i = tid; i < n; i += 256) s += (double)partials[i];
  for (int off = 32; off > 0; off >>= 1)
    s += __shfl_down(s, off, 64);
  if ((tid & 63) == 0) sred[tid >> 6] = s;
  __syncthreads();
  if (tid == 0) {
    double tot = 0.0;
#pragma unroll
    for (int i = 0; i < 4; i++) tot += sred[i];
    out[0] = (float)(1.0 - tot * invN);
  }
}

extern "C" void kernel_launch(void* const* d_in, const int* in_sizes, int n_in,
                              void* d_out, int out_size, void* d_ws, size_t ws_size,
                              hipStream_t stream) {
  const float* img1 = (const float*)d_in[0];
  const float* img2 = (const float*)d_in[1];
  float* out = (float*)d_out;
  float* partials = (float*)d_ws;

  const int planes = in_sizes[0] / (512 * 512);   // 96
  const int nBlocks = planes * 8 * 8;             // 6144, one 64x64 tile each

  GWH wh;
  {
    double g[WSZ], sum = 0.0;
    for (int i = 0; i < WSZ; i++) {
      const double x = (double)(i - WSZ / 2);
      g[i] = exp(-(x * x) / (2.0 * 1.5 * 1.5));
      sum += g[i];
    }
    for (int i = 0; i < WSZ; i++) {
      const _Float16 hf = (_Float16)(float)(g[i] / sum);
      unsigned short hb;
      memcpy(&hb, &hf, 2);
      wh.g2[i] = (unsigned)hb | ((unsigned)hb << 16);
    }
  }

  const double invN = 1.0 / (double)in_sizes[0];

  ssim_main_kernel<<<nBlocks, NTHREADS, 0, stream>>>(img1, img2, partials, wh);
  ssim_final_kernel<<<1, 256, 0, stream>>>(partials, out, nBlocks, invN);
}